// Round 8
// baseline (388.718 us; speedup 1.0000x reference)
//
#include <hip/hip_runtime.h>
#include <hip/hip_bf16.h>

// B=8, C=256, H=W=32, N=HW=1024.
// Pipeline (all GEMMs C[M,N] = A[M,K] · Bt[N,K]^T, both K-contiguous):
//  xT    = transpose(x) bf16                      [8][1024,256]
//  x1    = w1·xT^T + b1(row)                      [8][chan,hw]
//  x1T   = xT·w1^T + b1(col)   (stacked M=8192)   [8][hw,chan]
//  gT|rT = x1T·(wq||wv)^T + (bq||bv)(col)  stacked M=8192, N=2048, split out
//  S     = x1·gT^T (fp32)                         [8][chan,hw] ; C2 = S^T (algebra)
//  zs    = alpha * row-softmax(S)      bf16  -> x1tb (dead)
//  zc    = beta  * col-softmax(S)      bf16  -> gtb  (dead)
//  PT    = rT·zs^T + zc·x1^T           bf16  -> Sf   (dead)
//  out   = w2·PT^T + b2(row)           fp32
// gemm_v4: BM=256 BN=128 BK=64, FOUR waves (2Mx2N, 128x64/wave -> 64 MFMA
// per K-tile per wave), 3-buf counted-vmcnt(12) pipeline, R7-style pipelined
// register double-sets (ds_reads retire under 32-MFMA clusters), 1 wave/SIMD
// (512-VGPR budget, all-ILP hiding), chunk-XOR LDS swizzle (128B rows),
// bijective XCD block swizzle. 144 KB LDS, 1 block/CU.

typedef __attribute__((ext_vector_type(4))) float f4;
typedef __attribute__((ext_vector_type(8))) short s8;
typedef __attribute__((ext_vector_type(4))) unsigned short us4;
typedef __attribute__((ext_vector_type(8))) unsigned short us8;

__device__ __forceinline__ unsigned short f2bf(float f) {
    __hip_bfloat16 h = __float2bfloat16(f);
    return __builtin_bit_cast(unsigned short, h);
}

#define GAS(p) ((const __attribute__((address_space(1))) unsigned int*)(p))
#define LAS(p) ((__attribute__((address_space(3))) unsigned int*)(p))

// ---------------- weight fp32 -> bf16 conversion + bias concat ----------------
__global__ __launch_bounds__(256) void conv_weights(
    const float* __restrict__ w1, const float* __restrict__ wq,
    const float* __restrict__ wv, const float* __restrict__ w2,
    unsigned short* __restrict__ w1b, unsigned short* __restrict__ wqb,
    unsigned short* __restrict__ wvb, unsigned short* __restrict__ w2b,
    const float* __restrict__ bq, const float* __restrict__ bv,
    float* __restrict__ biasqv)
{
    long i = (long)blockIdx.x * 256 + threadIdx.x;  // float4 index
    if (i >= 655360) {                               // bias concat: 512 f4
        long j = i - 655360;
        if (j < 512) {
            f4 v = (j < 256) ? ((const f4*)bq)[j] : ((const f4*)bv)[j - 256];
            ((f4*)biasqv)[j] = v;
        }
        return;
    }
    const float* src; unsigned short* dst; long base;
    if (i < 65536)               { src = w1; dst = w1b; base = 0; }
    else if (i < 65536+262144)   { src = wq; dst = wqb; base = 65536; }
    else if (i < 65536+524288)   { src = wv; dst = wvb; base = 65536+262144; }
    else                         { src = w2; dst = w2b; base = 65536+524288; }
    long j = i - base;
    f4 v = ((const f4*)src)[j];
    us4 o;
    #pragma unroll
    for (int k = 0; k < 4; ++k) o[k] = f2bf(v[k]);
    ((us4*)dst)[j] = o;
}

// ---------------- x [8][256][1024] fp32 -> xT [8][1024][256] bf16 -------------
__global__ __launch_bounds__(256) void transpose_x(
    const float* __restrict__ x, unsigned short* __restrict__ xT)
{
    __shared__ float tl[32][33];
    const int b  = blockIdx.z;
    const int q0 = blockIdx.x * 32;
    const int c0 = blockIdx.y * 32;
    const int tx = threadIdx.x & 31, ty = threadIdx.x >> 5;  // ty 0..7
    #pragma unroll
    for (int j = 0; j < 4; ++j)
        tl[ty + j*8][tx] = x[((long)(b*256 + c0 + ty + j*8))*1024 + q0 + tx];
    __syncthreads();
    #pragma unroll
    for (int j = 0; j < 4; ++j)
        xT[((long)(b*1024 + q0 + ty + j*8))*256 + c0 + tx] = f2bf(tl[tx][ty + j*8]);
}

// ---------------- 4-wave big-ILP GEMM: 256x128, BK=64 -------------------------
// BIAS: 0 none, 1 row, 2 col. OUTF32: fp32 out. SPLIT: cols>=1024 -> Cv1.
// NPASS: 1 or 2 (dual accumulate). nt1: K-tiles (of 64) per pass (>= 2).
// Grid total MUST be % 8 == 0.
template<int BIAS, int OUTF32, int SPLIT, int NPASS>
__global__ __launch_bounds__(256, 1) void gemm_v4(
    const unsigned short* __restrict__ A0, const unsigned short* __restrict__ Bt0,
    const unsigned short* __restrict__ A1, const unsigned short* __restrict__ Bt1,
    long sA, long sB, int lda, int ldb,
    void* __restrict__ Cv0, void* __restrict__ Cv1, long sC, int ldc,
    const float* __restrict__ bias, int nt1)
{
    __shared__ __align__(16) unsigned short As[3][16384];   // 3 x 256x64 = 96 KB
    __shared__ __align__(16) unsigned short Bs[3][8192];    // 3 x 128x64 = 48 KB

    // bijective XCD swizzle (grid % 8 == 0): same-XCD blocks get contiguous tiles
    const int gx = gridDim.x, gy = gridDim.y;
    const int nwg = gx * gy * gridDim.z;
    int d = blockIdx.x + gx * (blockIdx.y + gy * blockIdx.z);
    int swz = (d & 7) * (nwg >> 3) + (d >> 3);
    const int bx = swz % gx; int tq = swz / gx;
    const int by = tq % gy;  const int bz = tq / gy;

    const int b  = bz;
    const int m0 = by * 256;
    const int n0 = bx * 128;
    const int t  = threadIdx.x;
    const int w  = t >> 6, l = t & 63;
    const int wr = w >> 1, wc = w & 1;          // 2 M-waves x 2 N-waves
    const int lr = l & 15, lg = l >> 4;         // frag row / k-group

    const unsigned short* A0b = A0  + (long)b * sA;
    const unsigned short* B0b = Bt0 + (long)b * sB;
    const unsigned short* A1b = (NPASS > 1) ? A1  + (long)b * sA : nullptr;
    const unsigned short* B1b = (NPASS > 1) ? Bt1 + (long)b * sB : nullptr;

    // staging: 1 instr/wave = 64 lanes x 16B = 8 rows of 64 elems (128B rows).
    // LDS dest linear (row = base + l>>3, chunk cs = l&7); global source chunk
    // pre-swizzled: gchunk = cs ^ (row&7) = (l&7) ^ ((l>>3)&7).
    const int rl  = l >> 3;
    const int gsw = ((l & 7) ^ (rl & 7)) * 8;   // element offset of 16B chunk

    const int NT = NPASS * nt1;

    auto stageA = [&](int sp, int bf) {         // 8 loads/wave: 256 rows total
        const unsigned short* Ap = A0b; int kt = sp * 64;
        if (NPASS > 1 && sp >= nt1) { Ap = A1b; kt = (sp - nt1) * 64; }
        #pragma unroll
        for (int i = 0; i < 8; ++i) {
            const int rb = w*64 + i*8;
            __builtin_amdgcn_global_load_lds(GAS(Ap + (long)(m0 + rb + rl)*lda + kt + gsw),
                                             LAS(&As[bf][rb*64]), 16, 0, 0);
        }
    };
    auto stageB = [&](int sp, int bf) {         // 4 loads/wave: 128 rows total
        const unsigned short* Bp = B0b; int kt = sp * 64;
        if (NPASS > 1 && sp >= nt1) { Bp = B1b; kt = (sp - nt1) * 64; }
        #pragma unroll
        for (int i = 0; i < 4; ++i) {
            const int rb = w*32 + i*8;
            __builtin_amdgcn_global_load_lds(GAS(Bp + (long)(n0 + rb + rl)*ldb + kt + gsw),
                                             LAS(&Bs[bf][rb*64]), 16, 0, 0);
        }
    };

    f4 acc[8][4];
    #pragma unroll
    for (int i = 0; i < 8; ++i)
        #pragma unroll
        for (int j = 0; j < 4; ++j) acc[i][j] = (f4){0.f, 0.f, 0.f, 0.f};

    // prologue: stage K-tiles 0 and 1 (12 loads each); wait tile 0 only
    stageA(0, 0); stageB(0, 0);
    stageA(1, 1); stageB(1, 1);
    asm volatile("s_waitcnt vmcnt(12)" ::: "memory");
    __builtin_amdgcn_sched_barrier(0);
    __builtin_amdgcn_s_barrier();

    // frag register double-set (static names, rule #20)
    s8 a0[8], b0[4], a1f[8], b1f[4];

    // initial: set0 <- (tile 0, kk=0)
    #pragma unroll
    for (int m = 0; m < 8; ++m) {
        const int R = wr*128 + m*16 + lr;
        a0[m] = *(const s8*)&As[0][R*64 + ((lg ^ (R & 7)) * 8)];
    }
    #pragma unroll
    for (int n = 0; n < 4; ++n) {
        const int R = wc*64 + n*16 + lr;
        b0[n] = *(const s8*)&Bs[0][R*64 + ((lg ^ (R & 7)) * 8)];
    }
    asm volatile("s_waitcnt lgkmcnt(0)" ::: "memory");
    __builtin_amdgcn_sched_barrier(0);

    int buf = 0;
    for (int s = 0; s < NT; ++s) {
        int bn  = buf + 2; if (bn  >= 3) bn  -= 3;   // staging target (t+2)
        int bx1 = buf + 1; if (bx1 >= 3) bx1 -= 3;   // next tile's buffer

        // ---- ph0: read set1 <- (s, kk1); stageA(s+2); MFMA(set0) x32 ----
        #pragma unroll
        for (int m = 0; m < 8; ++m) {
            const int R = wr*128 + m*16 + lr;
            a1f[m] = *(const s8*)&As[buf][R*64 + (((4 + lg) ^ (R & 7)) * 8)];
        }
        #pragma unroll
        for (int n = 0; n < 4; ++n) {
            const int R = wc*64 + n*16 + lr;
            b1f[n] = *(const s8*)&Bs[buf][R*64 + (((4 + lg) ^ (R & 7)) * 8)];
        }
        if (s + 2 < NT) stageA(s + 2, bn);
        __builtin_amdgcn_s_setprio(1);
        #pragma unroll
        for (int m = 0; m < 8; ++m)
            #pragma unroll
            for (int n = 0; n < 4; ++n)
                acc[m][n] = __builtin_amdgcn_mfma_f32_16x16x32_bf16(a0[m], b0[n], acc[m][n], 0, 0, 0);
        __builtin_amdgcn_s_setprio(0);
        asm volatile("s_waitcnt lgkmcnt(0)" ::: "memory");   // set1 retired under MFMA
        __builtin_amdgcn_sched_barrier(0);

        // ---- ph1: stageB(s+2); vmcnt to t+1; barrier; read set0 <- (s+1,kk0);
        //           MFMA(set1) x32 ----
        if (s + 1 < NT) {
            if (s + 2 < NT) {
                stageB(s + 2, bn);
                asm volatile("s_waitcnt vmcnt(12)" ::: "memory");  // t+1's 12 done
            } else {
                asm volatile("s_waitcnt vmcnt(0)" ::: "memory");
            }
            __builtin_amdgcn_sched_barrier(0);
            __builtin_amdgcn_s_barrier();
            #pragma unroll
            for (int m = 0; m < 8; ++m) {
                const int R = wr*128 + m*16 + lr;
                a0[m] = *(const s8*)&As[bx1][R*64 + ((lg ^ (R & 7)) * 8)];
            }
            #pragma unroll
            for (int n = 0; n < 4; ++n) {
                const int R = wc*64 + n*16 + lr;
                b0[n] = *(const s8*)&Bs[bx1][R*64 + ((lg ^ (R & 7)) * 8)];
            }
            __builtin_amdgcn_s_setprio(1);
            #pragma unroll
            for (int m = 0; m < 8; ++m)
                #pragma unroll
                for (int n = 0; n < 4; ++n)
                    acc[m][n] = __builtin_amdgcn_mfma_f32_16x16x32_bf16(a1f[m], b1f[n], acc[m][n], 0, 0, 0);
            __builtin_amdgcn_s_setprio(0);
            asm volatile("s_waitcnt lgkmcnt(0)" ::: "memory");  // set0 retired
            __builtin_amdgcn_sched_barrier(0);
        } else {
            __builtin_amdgcn_s_setprio(1);
            #pragma unroll
            for (int m = 0; m < 8; ++m)
                #pragma unroll
                for (int n = 0; n < 4; ++n)
                    acc[m][n] = __builtin_amdgcn_mfma_f32_16x16x32_bf16(a1f[m], b1f[n], acc[m][n], 0, 0, 0);
            __builtin_amdgcn_s_setprio(0);
        }

        buf = bx1;
    }

    void* Cd = Cv0; int nbase = n0;
    if (SPLIT && n0 >= 1024) { Cd = Cv1; nbase = n0 - 1024; }

    const int rbase = lg * 4;
    #pragma unroll
    for (int m = 0; m < 8; ++m) {
        #pragma unroll
        for (int n = 0; n < 4; ++n) {
            const int row  = m0 + wr*128 + m*16 + rbase;
            const int col  = nbase + wc*64 + n*16 + lr;
            const int bcol = n0    + wc*64 + n*16 + lr;
            #pragma unroll
            for (int j = 0; j < 4; ++j) {
                float v = acc[m][n][j];
                if (BIAS == 1) v += bias[row + j];
                else if (BIAS == 2) v += bias[bcol];
                const long idx = (long)b*sC + (long)(row + j)*ldc + col;
                if (OUTF32) ((float*)Cd)[idx] = v;
                else ((unsigned short*)Cd)[idx] = f2bf(v);
            }
        }
    }
}

// ---------------- 128x128 pipelined GEMM (small shapes: out projection) -------
template<int BIAS, int OUTF32, int NT1, int NBUF>
__global__ __launch_bounds__(256) void gemm_pipe(
    const unsigned short* __restrict__ A0, const unsigned short* __restrict__ Bt0,
    long sA, long sB, int lda, int ldb,
    void* __restrict__ Cv0, long sC, int ldc,
    const float* __restrict__ bias)
{
    constexpr int NT = NT1;
    __shared__ __align__(16) unsigned short As[NBUF][4096];
    __shared__ __align__(16) unsigned short Bs[NBUF][4096];

    const int gx = gridDim.x, gy = gridDim.y;
    const int nwg = gx * gy * gridDim.z;
    int d = blockIdx.x + gx * (blockIdx.y + gy * blockIdx.z);
    int swz = (d & 7) * (nwg >> 3) + (d >> 3);
    const int bx = swz % gx; int tq = swz / gx;
    const int by = tq % gy;  const int bz = tq / gy;

    const int b  = bz;
    const int m0 = by * 128;
    const int n0 = bx * 128;
    const int t  = threadIdx.x;
    const int w  = t >> 6, l = t & 63;
    const int wr = w >> 1, wc = w & 1;
    const int lr = l & 15;

    const unsigned short* A0b = A0  + (long)b * sA;
    const unsigned short* B0b = Bt0 + (long)b * sB;

    const int rA   = w*32 + (l >> 2);
    const int cswz = ((l & 3) ^ ((l >> 3) & 3)) * 8;
    const int swzr = (((l >> 4) ^ ((lr >> 1) & 3)) * 8);

    f4 acc[4][4];
    #pragma unroll
    for (int i = 0; i < 4; ++i)
        #pragma unroll
        for (int j = 0; j < 4; ++j) acc[i][j] = (f4){0.f, 0.f, 0.f, 0.f};

    auto stage = [&](int sp, int bf) {
        const int kt = sp * 32;
        __builtin_amdgcn_global_load_lds(GAS(A0b + (long)(m0 + rA     )*lda + kt + cswz), LAS(&As[bf][w*1024      ]), 16, 0, 0);
        __builtin_amdgcn_global_load_lds(GAS(A0b + (long)(m0 + rA + 16)*lda + kt + cswz), LAS(&As[bf][w*1024 + 512]), 16, 0, 0);
        __builtin_amdgcn_global_load_lds(GAS(B0b + (long)(n0 + rA     )*ldb + kt + cswz), LAS(&Bs[bf][w*1024      ]), 16, 0, 0);
        __builtin_amdgcn_global_load_lds(GAS(B0b + (long)(n0 + rA + 16)*ldb + kt + cswz), LAS(&Bs[bf][w*1024 + 512]), 16, 0, 0);
    };

    #pragma unroll
    for (int dpl = 0; dpl < NBUF - 1; ++dpl) stage(dpl, dpl);

    int buf = 0;
    for (int s = 0; s < NT; ++s) {
        if (NBUF >= 4 && s + 2 < NT) asm volatile("s_waitcnt vmcnt(8)" ::: "memory");
        else if (s + 1 < NT)         asm volatile("s_waitcnt vmcnt(4)" ::: "memory");
        else                         asm volatile("s_waitcnt vmcnt(0)" ::: "memory");
        __builtin_amdgcn_s_barrier();
        __builtin_amdgcn_sched_barrier(0);

        s8 aF[4], bF[4];
        #pragma unroll
        for (int m = 0; m < 4; ++m) aF[m] = *(const s8*)&As[buf][(wr*64 + m*16 + lr)*32 + swzr];
        #pragma unroll
        for (int n = 0; n < 4; ++n) bF[n] = *(const s8*)&Bs[buf][(wc*64 + n*16 + lr)*32 + swzr];

        if (s + NBUF - 1 < NT) {
            int bn = buf + NBUF - 1; if (bn >= NBUF) bn -= NBUF;
            stage(s + NBUF - 1, bn);
        }

        __builtin_amdgcn_s_setprio(1);
        #pragma unroll
        for (int m = 0; m < 4; ++m)
            #pragma unroll
            for (int n = 0; n < 4; ++n)
                acc[m][n] = __builtin_amdgcn_mfma_f32_16x16x32_bf16(aF[m], bF[n], acc[m][n], 0, 0, 0);
        __builtin_amdgcn_s_setprio(0);

        if (++buf == NBUF) buf = 0;
    }

    const int rbase = (l >> 4) * 4;
    #pragma unroll
    for (int m = 0; m < 4; ++m) {
        #pragma unroll
        for (int n = 0; n < 4; ++n) {
            const int row = m0 + wr*64 + m*16 + rbase;
            const int col = n0 + wc*64 + n*16 + lr;
            #pragma unroll
            for (int j = 0; j < 4; ++j) {
                float v = acc[m][n][j];
                if (BIAS == 1) v += bias[row + j];
                else if (BIAS == 2) v += bias[col];
                const long idx = (long)b*sC + (long)(row + j)*ldc + col;
                if (OUTF32) ((float*)Cv0)[idx] = v;
                else ((unsigned short*)Cv0)[idx] = f2bf(v);
            }
        }
    }
}

// ---------------- row softmax: zs[r][k] = scale * softmax_k(S[r][k]) ----------
__global__ __launch_bounds__(256) void row_softmax(
    const float* __restrict__ S, unsigned short* __restrict__ Z,
    const float* __restrict__ scale_p)
{
    const int wid = threadIdx.x >> 6, l = threadIdx.x & 63;
    const long row = (long)blockIdx.x * 4 + wid;   // 8192 rows total
    const float* src = S + row * 1024;
    f4 v[4];
    #pragma unroll
    for (int i = 0; i < 4; ++i) v[i] = *(const f4*)&src[(i*64 + l)*4];
    float m = -3.4e38f;
    #pragma unroll
    for (int i = 0; i < 4; ++i)
        #pragma unroll
        for (int j = 0; j < 4; ++j) m = fmaxf(m, v[i][j]);
    #pragma unroll
    for (int off = 32; off; off >>= 1) m = fmaxf(m, __shfl_xor(m, off));
    float s = 0.f;
    #pragma unroll
    for (int i = 0; i < 4; ++i)
        #pragma unroll
        for (int j = 0; j < 4; ++j) { v[i][j] = __expf(v[i][j] - m); s += v[i][j]; }
    #pragma unroll
    for (int off = 32; off; off >>= 1) s += __shfl_xor(s, off);
    const float c = scale_p[0] / s;
    #pragma unroll
    for (int i = 0; i < 4; ++i) {
        us4 o;
        #pragma unroll
        for (int j = 0; j < 4; ++j) o[j] = f2bf(v[i][j] * c);
        *(us4*)&Z[row*1024 + (long)(i*64 + l)*4] = o;
    }
}

// ---------------- column stats: online max+sum per column ---------------------
__global__ __launch_bounds__(256) void col_stats(
    const float* __restrict__ S, float* __restrict__ cm, float* __restrict__ cs)
{
    __shared__ float pm[4][64], ps[4][64];
    const int b  = blockIdx.y;
    const int ci = threadIdx.x & 63, ks = threadIdx.x >> 6;
    const int q  = blockIdx.x * 64 + ci;
    const float* Sb = S + (long)b * 1048576 + q;
    float m = -3.4e38f, s = 0.f;
    for (int k = ks*256; k < ks*256 + 256; ++k) {
        float v = Sb[(long)k * 1024];
        float dlt = v - m;
        float ed = __expf(-fabsf(dlt));
        if (dlt > 0.f) { s = s * ed + 1.f; m = v; } else s += ed;
    }
    pm[ks][ci] = m; ps[ks][ci] = s;
    __syncthreads();
    if (threadIdx.x < 64) {
        float M = pm[0][ci];
        #pragma unroll
        for (int i = 1; i < 4; ++i) M = fmaxf(M, pm[i][ci]);
        float Ssum = 0.f;
        #pragma unroll
        for (int i = 0; i < 4; ++i) Ssum += ps[i][ci] * __expf(pm[i][ci] - M);
        cm[b*1024 + q] = M;
        cs[b*1024 + q] = Ssum;
    }
}

// ---------------- column softmax write: zc[q][k] = sc*exp(S[k][q]-m)/s --------
__global__ __launch_bounds__(256) void col_write(
    const float* __restrict__ S, const float* __restrict__ cm,
    const float* __restrict__ cs, unsigned short* __restrict__ Z,
    const float* __restrict__ scale_p)
{
    const int b  = blockIdx.z;
    const int k0 = blockIdx.y * 64;
    const int q  = blockIdx.x * 256 + threadIdx.x;
    const float m   = cm[b*1024 + q];
    const float inv = scale_p[0] / cs[b*1024 + q];
    const float* Sb = S + (long)b * 1048576 + q;
    unsigned short* Zb = Z + (long)b * 1048576 + (long)q * 1024 + k0;
    #pragma unroll
    for (int c8 = 0; c8 < 8; ++c8) {
        us8 o;
        #pragma unroll
        for (int j = 0; j < 8; ++j)
            o[j] = f2bf(inv * __expf(Sb[(long)(k0 + c8*8 + j) * 1024] - m));
        *(us8*)&Zb[c8*8] = o;
    }
}

// -----------------------------------------------------------------------------
extern "C" void kernel_launch(void* const* d_in, const int* in_sizes, int n_in,
                              void* d_out, int out_size, void* d_ws, size_t ws_size,
                              hipStream_t stream)
{
    const float* x     = (const float*)d_in[0];
    const float* w1    = (const float*)d_in[1];
    const float* b1    = (const float*)d_in[2];
    const float* wq    = (const float*)d_in[3];
    const float* bq    = (const float*)d_in[4];
    const float* wv    = (const float*)d_in[5];
    const float* bv    = (const float*)d_in[6];
    const float* w2    = (const float*)d_in[7];
    const float* b2    = (const float*)d_in[8];
    const float* alpha = (const float*)d_in[9];
    const float* beta  = (const float*)d_in[10];
    float* out = (float*)d_out;

    char* ws = (char*)d_ws;
    size_t off = 0;
    auto alloc = [&](size_t bytes) -> void* {
        void* p = ws + off; off += (bytes + 255) & ~(size_t)255; return p;
    };
    unsigned short* w1b   = (unsigned short*)alloc(1024L*256*2);      // .5 MB
    unsigned short* wqvb  = (unsigned short*)alloc(2048L*1024*2);     //  4 MB (wq||wv)
    unsigned short* w2b   = (unsigned short*)alloc(256L*1024*2);      // .5 MB
    float*          biasqv= (float*)alloc(2048L*4);                   //  8 KB
    float*          cmv   = (float*)alloc(8L*1024*4);                 // 32 KB
    float*          csv   = (float*)alloc(8L*1024*4);                 // 32 KB
    unsigned short* xTb   = (unsigned short*)alloc(8L*1024*256*2);    //  4 MB
    unsigned short* x1b   = (unsigned short*)alloc(8L*1024*1024*2);   // 16 MB
    unsigned short* x1tb  = (unsigned short*)alloc(8L*1024*1024*2);   // 16 MB
    unsigned short* gtb   = (unsigned short*)alloc(8L*1024*1024*2);   // 16 MB
    unsigned short* rtb   = (unsigned short*)alloc(8L*1024*1024*2);   // 16 MB
    float*          Sf    = (float*)alloc(8L*1024*1024*4);            // 32 MB
    // lifetime aliases:
    unsigned short* zsb = x1tb;                 // x1tb dead after gT/rT GEMM
    unsigned short* zcb = gtb;                  // gtb dead after S GEMM
    unsigned short* Ptb = (unsigned short*)Sf;  // Sf dead after softmaxes

    const long S1M = 1048576;

    conv_weights<<<2562, 256, 0, stream>>>(w1, wq, wv, w2, w1b, wqvb, wqvb + S1M, w2b, bq, bv, biasqv);
    transpose_x<<<dim3(32, 8, 8), 256, 0, stream>>>(x, xTb);

    // x1 = w1·xT^T + b1(row)               [chan,hw], z-batched (256 blocks)
    gemm_v4<1,0,0,1><<<dim3(8, 4, 8), 256, 0, stream>>>(
        w1b, xTb, nullptr, nullptr, 0, 262144, 256, 256, x1b, nullptr, S1M, 1024, b1, 4);
    // x1T = xT·w1^T + b1(col)              stacked M=8192 (256 blocks)
    gemm_v4<2,0,0,1><<<dim3(8, 32, 1), 256, 0, stream>>>(
        xTb, w1b, nullptr, nullptr, 0, 0, 256, 256, x1tb, nullptr, 0, 1024, b1, 4);
    // gT|rT = x1T·(wq||wv)^T + bias(col)   stacked M=8192, N=2048, split (512 blocks)
    gemm_v4<2,0,1,1><<<dim3(16, 32, 1), 256, 0, stream>>>(
        x1tb, wqvb, nullptr, nullptr, 0, 0, 1024, 1024, gtb, rtb, 0, 1024, biasqv, 16);
    // S = x1·gT^T (fp32)                   z-batched (256 blocks)
    gemm_v4<0,1,0,1><<<dim3(8, 4, 8), 256, 0, stream>>>(
        x1b, gtb, nullptr, nullptr, S1M, S1M, 1024, 1024, Sf, nullptr, S1M, 1024, nullptr, 16);
    // zs = alpha * row-softmax(S); zc = beta * col-softmax(S)   (C2 = S^T)
    row_softmax<<<2048, 256, 0, stream>>>(Sf, zsb, alpha);
    col_stats<<<dim3(16, 8), 256, 0, stream>>>(Sf, cmv, csv);
    col_write<<<dim3(4, 16, 8), 256, 0, stream>>>(Sf, cmv, csv, zcb, beta);
    // PT = rT·zs^T + zc·x1^T               dual-pass accumulate (256 blocks)
    gemm_v4<0,0,0,2><<<dim3(8, 4, 8), 256, 0, stream>>>(
        rtb, zsb, zcb, x1b, S1M, S1M, 1024, 1024, Ptb, nullptr, S1M, 1024, nullptr, 16);
    // out = w2·PT^T + b2(row), fp32        (128 blocks, depth-3)
    gemm_pipe<1,1,32,4><<<dim3(8, 2, 8), 256, 0, stream>>>(
        w2b, Ptb, 0, S1M, 1024, 1024, out, 262144, 1024, b2);
}

// Round 10
// 180.426 us; speedup vs baseline: 2.1544x; 2.1544x over previous
//
#include <hip/hip_runtime.h>
#include <hip/hip_bf16.h>

// B=8, C=256, H=W=32, N=HW=1024.
// Pipeline (all GEMMs C[M,N] = A[M,K] · Bt[N,K]^T, both K-contiguous):
//  xT    = transpose(x) bf16                      [8][1024,256]
//  x1    = w1·xT^T + b1(row)                      [8][chan,hw]
//  x1T   = xT·w1^T + b1(col)   (stacked M=8192)   [8][hw,chan]
//  gT|rT = x1T·(wq||wv)^T + (bq||bv)(col)  stacked M=8192, N=2048, split out
//  S     = x1·gT^T (fp32)                         [8][chan,hw] ; C2 = S^T (algebra)
//  zs    = alpha * row-softmax(S)      bf16  -> x1tb (dead)
//  zc    = beta  * col-softmax(S)      bf16  -> gtb  (dead)
//  PT    = rT·zs^T + zc·x1^T           bf16  -> Sf   (dead)
//  out   = w2·PT^T + b2(row)           fp32
// gemm256: BM=256 BN=128 BK=64, 8 waves (4Mx2N), 3-buf counted-vmcnt pipeline
// + software-pipelined frag reads (R7, verified 188 us). col_write now does a
// 64x64 LDS transpose so zc stores are 128B-contiguous per q-row (was 16B
// scattered at 2KB stride -> ~4x write amplification).

typedef __attribute__((ext_vector_type(4))) float f4;
typedef __attribute__((ext_vector_type(8))) short s8;
typedef __attribute__((ext_vector_type(4))) unsigned short us4;
typedef __attribute__((ext_vector_type(8))) unsigned short us8;

__device__ __forceinline__ unsigned short f2bf(float f) {
    __hip_bfloat16 h = __float2bfloat16(f);
    return __builtin_bit_cast(unsigned short, h);
}

#define GAS(p) ((const __attribute__((address_space(1))) unsigned int*)(p))
#define LAS(p) ((__attribute__((address_space(3))) unsigned int*)(p))

// ---------------- weight fp32 -> bf16 conversion + bias concat ----------------
__global__ __launch_bounds__(256) void conv_weights(
    const float* __restrict__ w1, const float* __restrict__ wq,
    const float* __restrict__ wv, const float* __restrict__ w2,
    unsigned short* __restrict__ w1b, unsigned short* __restrict__ wqb,
    unsigned short* __restrict__ wvb, unsigned short* __restrict__ w2b,
    const float* __restrict__ bq, const float* __restrict__ bv,
    float* __restrict__ biasqv)
{
    long i = (long)blockIdx.x * 256 + threadIdx.x;  // float4 index
    if (i >= 655360) {                               // bias concat: 512 f4
        long j = i - 655360;
        if (j < 512) {
            f4 v = (j < 256) ? ((const f4*)bq)[j] : ((const f4*)bv)[j - 256];
            ((f4*)biasqv)[j] = v;
        }
        return;
    }
    const float* src; unsigned short* dst; long base;
    if (i < 65536)               { src = w1; dst = w1b; base = 0; }
    else if (i < 65536+262144)   { src = wq; dst = wqb; base = 65536; }
    else if (i < 65536+524288)   { src = wv; dst = wvb; base = 65536+262144; }
    else                         { src = w2; dst = w2b; base = 65536+524288; }
    long j = i - base;
    f4 v = ((const f4*)src)[j];
    us4 o;
    #pragma unroll
    for (int k = 0; k < 4; ++k) o[k] = f2bf(v[k]);
    ((us4*)dst)[j] = o;
}

// ---------------- x [8][256][1024] fp32 -> xT [8][1024][256] bf16 -------------
__global__ __launch_bounds__(256) void transpose_x(
    const float* __restrict__ x, unsigned short* __restrict__ xT)
{
    __shared__ float tl[32][33];
    const int b  = blockIdx.z;
    const int q0 = blockIdx.x * 32;
    const int c0 = blockIdx.y * 32;
    const int tx = threadIdx.x & 31, ty = threadIdx.x >> 5;  // ty 0..7
    #pragma unroll
    for (int j = 0; j < 4; ++j)
        tl[ty + j*8][tx] = x[((long)(b*256 + c0 + ty + j*8))*1024 + q0 + tx];
    __syncthreads();
    #pragma unroll
    for (int j = 0; j < 4; ++j)
        xT[((long)(b*1024 + q0 + ty + j*8))*256 + c0 + tx] = f2bf(tl[tx][ty + j*8]);
}

// ---------------- big-tile GEMM: 256x128, BK=64, 8 waves, piped reads ---------
// BIAS: 0 none, 1 row, 2 col. OUTF32: fp32 out. SPLIT: cols>=1024 -> Cv1.
// NPASS: 1 or 2 (dual accumulate). nt1: K-tiles (of 64) per pass (>= 3).
// Grid total MUST be % 8 == 0.
template<int BIAS, int OUTF32, int SPLIT, int NPASS>
__global__ __launch_bounds__(512, 2) void gemm256(
    const unsigned short* __restrict__ A0, const unsigned short* __restrict__ Bt0,
    const unsigned short* __restrict__ A1, const unsigned short* __restrict__ Bt1,
    long sA, long sB, int lda, int ldb,
    void* __restrict__ Cv0, void* __restrict__ Cv1, long sC, int ldc,
    const float* __restrict__ bias, int nt1)
{
    __shared__ __align__(16) unsigned short As[3][16384];   // 3 x 256x64 = 96 KB
    __shared__ __align__(16) unsigned short Bs[3][8192];    // 3 x 128x64 = 48 KB

    // bijective XCD swizzle (grid % 8 == 0): same-XCD blocks get contiguous tiles
    const int gx = gridDim.x, gy = gridDim.y;
    const int nwg = gx * gy * gridDim.z;
    int d = blockIdx.x + gx * (blockIdx.y + gy * blockIdx.z);
    int swz = (d & 7) * (nwg >> 3) + (d >> 3);
    const int bx = swz % gx; int tq = swz / gx;
    const int by = tq % gy;  const int bz = tq / gy;

    const int b  = bz;
    const int m0 = by * 256;
    const int n0 = bx * 128;
    const int t  = threadIdx.x;
    const int w  = t >> 6, l = t & 63;
    const int wr = w >> 1, wc = w & 1;          // 4 M-waves x 2 N-waves
    const int lr = l & 15, lg = l >> 4;         // frag row / k-group

    const unsigned short* A0b = A0  + (long)b * sA;
    const unsigned short* B0b = Bt0 + (long)b * sB;
    const unsigned short* A1b = (NPASS > 1) ? A1  + (long)b * sA : nullptr;
    const unsigned short* B1b = (NPASS > 1) ? Bt1 + (long)b * sB : nullptr;

    // staging: 1 instr/wave = 64 lanes x 16B = 8 rows of 64 elems (128B rows).
    // LDS dest linear (row = base + l>>3, chunk cs = l&7); global source chunk
    // pre-swizzled: gchunk = cs ^ (row&7) = (l&7) ^ ((l>>3)&7).
    const int rl  = l >> 3;
    const int gsw = ((l & 7) ^ (rl & 7)) * 8;   // element offset of 16B chunk

    const int NT = NPASS * nt1;

    auto stageA = [&](int sp, int bf) {         // 4 loads: 256 rows
        const unsigned short* Ap = A0b; int kt = sp * 64;
        if (NPASS > 1 && sp >= nt1) { Ap = A1b; kt = (sp - nt1) * 64; }
        #pragma unroll
        for (int i = 0; i < 4; ++i) {
            const int rb = w*32 + i*8;
            __builtin_amdgcn_global_load_lds(GAS(Ap + (long)(m0 + rb + rl)*lda + kt + gsw),
                                             LAS(&As[bf][rb*64]), 16, 0, 0);
        }
    };
    auto stageB = [&](int sp, int bf) {         // 2 loads: 128 rows
        const unsigned short* Bp = B0b; int kt = sp * 64;
        if (NPASS > 1 && sp >= nt1) { Bp = B1b; kt = (sp - nt1) * 64; }
        #pragma unroll
        for (int i = 0; i < 2; ++i) {
            const int rb = w*16 + i*8;
            __builtin_amdgcn_global_load_lds(GAS(Bp + (long)(n0 + rb + rl)*ldb + kt + gsw),
                                             LAS(&Bs[bf][rb*64]), 16, 0, 0);
        }
    };

    f4 acc[4][4];
    #pragma unroll
    for (int i = 0; i < 4; ++i)
        #pragma unroll
        for (int j = 0; j < 4; ++j) acc[i][j] = (f4){0.f, 0.f, 0.f, 0.f};

    // prologue: stage K-tiles 0 and 1 (6 loads each); wait tile 0 only
    stageA(0, 0); stageB(0, 0);
    stageA(1, 1); stageB(1, 1);
    asm volatile("s_waitcnt vmcnt(6)" ::: "memory");
    __builtin_amdgcn_sched_barrier(0);
    __builtin_amdgcn_s_barrier();

    // frag register double-set (static names, rule #20)
    s8 a0[4], b0[4], a1f[4], b1f[4];

    // initial: set0 <- (tile 0, kk=0)
    #pragma unroll
    for (int m = 0; m < 4; ++m) {
        const int R = wr*64 + m*16 + lr;
        a0[m] = *(const s8*)&As[0][R*64 + ((lg ^ (R & 7)) * 8)];
    }
    #pragma unroll
    for (int n = 0; n < 4; ++n) {
        const int R = wc*64 + n*16 + lr;
        b0[n] = *(const s8*)&Bs[0][R*64 + ((lg ^ (R & 7)) * 8)];
    }
    asm volatile("s_waitcnt lgkmcnt(0)" ::: "memory");
    __builtin_amdgcn_sched_barrier(0);

    int buf = 0;
    for (int s = 0; s < NT; ++s) {
        int bn = buf + 2; if (bn >= 3) bn -= 3;   // staging target (t+2)
        int bx1 = buf + 1; if (bx1 >= 3) bx1 -= 3; // next tile's buffer

        // ---- ph0: load set1 <- (s, kk1); stageA(s+2); MFMA(set0) ----
        #pragma unroll
        for (int m = 0; m < 4; ++m) {
            const int R = wr*64 + m*16 + lr;
            a1f[m] = *(const s8*)&As[buf][R*64 + (((4 + lg) ^ (R & 7)) * 8)];
        }
        #pragma unroll
        for (int n = 0; n < 4; ++n) {
            const int R = wc*64 + n*16 + lr;
            b1f[n] = *(const s8*)&Bs[buf][R*64 + (((4 + lg) ^ (R & 7)) * 8)];
        }
        if (s + 2 < NT) stageA(s + 2, bn);
        __builtin_amdgcn_s_setprio(1);
        #pragma unroll
        for (int m = 0; m < 4; ++m)
            #pragma unroll
            for (int n = 0; n < 4; ++n)
                acc[m][n] = __builtin_amdgcn_mfma_f32_16x16x32_bf16(a0[m], b0[n], acc[m][n], 0, 0, 0);
        __builtin_amdgcn_s_setprio(0);
        asm volatile("s_waitcnt lgkmcnt(0)" ::: "memory");   // set1 retired (covered by MFMA)
        __builtin_amdgcn_sched_barrier(0);

        // ---- ph1: barrier to t+1; load set0 <- (s+1, kk0); stageB(s+2); MFMA(set1) ----
        if (s + 1 < NT) {
            if (s + 2 < NT) asm volatile("s_waitcnt vmcnt(4)" ::: "memory");  // t+1's 6 done
            else            asm volatile("s_waitcnt vmcnt(0)" ::: "memory");
            __builtin_amdgcn_sched_barrier(0);
            __builtin_amdgcn_s_barrier();
            #pragma unroll
            for (int m = 0; m < 4; ++m) {
                const int R = wr*64 + m*16 + lr;
                a0[m] = *(const s8*)&As[bx1][R*64 + ((lg ^ (R & 7)) * 8)];
            }
            #pragma unroll
            for (int n = 0; n < 4; ++n) {
                const int R = wc*64 + n*16 + lr;
                b0[n] = *(const s8*)&Bs[bx1][R*64 + ((lg ^ (R & 7)) * 8)];
            }
            if (s + 2 < NT) stageB(s + 2, bn);
            __builtin_amdgcn_s_setprio(1);
            #pragma unroll
            for (int m = 0; m < 4; ++m)
                #pragma unroll
                for (int n = 0; n < 4; ++n)
                    acc[m][n] = __builtin_amdgcn_mfma_f32_16x16x32_bf16(a1f[m], b1f[n], acc[m][n], 0, 0, 0);
            __builtin_amdgcn_s_setprio(0);
            asm volatile("s_waitcnt lgkmcnt(0)" ::: "memory");  // set0 retired
            __builtin_amdgcn_sched_barrier(0);
        } else {
            __builtin_amdgcn_s_setprio(1);
            #pragma unroll
            for (int m = 0; m < 4; ++m)
                #pragma unroll
                for (int n = 0; n < 4; ++n)
                    acc[m][n] = __builtin_amdgcn_mfma_f32_16x16x32_bf16(a1f[m], b1f[n], acc[m][n], 0, 0, 0);
            __builtin_amdgcn_s_setprio(0);
        }

        buf = bx1;
    }

    void* Cd = Cv0; int nbase = n0;
    if (SPLIT && n0 >= 1024) { Cd = Cv1; nbase = n0 - 1024; }

    const int rbase = lg * 4;
    #pragma unroll
    for (int m = 0; m < 4; ++m) {
        #pragma unroll
        for (int n = 0; n < 4; ++n) {
            const int row  = m0 + wr*64 + m*16 + rbase;
            const int col  = nbase + wc*64 + n*16 + lr;
            const int bcol = n0    + wc*64 + n*16 + lr;
            #pragma unroll
            for (int j = 0; j < 4; ++j) {
                float v = acc[m][n][j];
                if (BIAS == 1) v += bias[row + j];
                else if (BIAS == 2) v += bias[bcol];
                const long idx = (long)b*sC + (long)(row + j)*ldc + col;
                if (OUTF32) ((float*)Cd)[idx] = v;
                else ((unsigned short*)Cd)[idx] = f2bf(v);
            }
        }
    }
}

// ---------------- 128x128 pipelined GEMM (small shapes: out projection) -------
template<int BIAS, int OUTF32, int NT1, int NBUF>
__global__ __launch_bounds__(256) void gemm_pipe(
    const unsigned short* __restrict__ A0, const unsigned short* __restrict__ Bt0,
    long sA, long sB, int lda, int ldb,
    void* __restrict__ Cv0, long sC, int ldc,
    const float* __restrict__ bias)
{
    constexpr int NT = NT1;
    __shared__ __align__(16) unsigned short As[NBUF][4096];
    __shared__ __align__(16) unsigned short Bs[NBUF][4096];

    const int gx = gridDim.x, gy = gridDim.y;
    const int nwg = gx * gy * gridDim.z;
    int d = blockIdx.x + gx * (blockIdx.y + gy * blockIdx.z);
    int swz = (d & 7) * (nwg >> 3) + (d >> 3);
    const int bx = swz % gx; int tq = swz / gx;
    const int by = tq % gy;  const int bz = tq / gy;

    const int b  = bz;
    const int m0 = by * 128;
    const int n0 = bx * 128;
    const int t  = threadIdx.x;
    const int w  = t >> 6, l = t & 63;
    const int wr = w >> 1, wc = w & 1;
    const int lr = l & 15;

    const unsigned short* A0b = A0  + (long)b * sA;
    const unsigned short* B0b = Bt0 + (long)b * sB;

    const int rA   = w*32 + (l >> 2);
    const int cswz = ((l & 3) ^ ((l >> 3) & 3)) * 8;
    const int swzr = (((l >> 4) ^ ((lr >> 1) & 3)) * 8);

    f4 acc[4][4];
    #pragma unroll
    for (int i = 0; i < 4; ++i)
        #pragma unroll
        for (int j = 0; j < 4; ++j) acc[i][j] = (f4){0.f, 0.f, 0.f, 0.f};

    auto stage = [&](int sp, int bf) {
        const int kt = sp * 32;
        __builtin_amdgcn_global_load_lds(GAS(A0b + (long)(m0 + rA     )*lda + kt + cswz), LAS(&As[bf][w*1024      ]), 16, 0, 0);
        __builtin_amdgcn_global_load_lds(GAS(A0b + (long)(m0 + rA + 16)*lda + kt + cswz), LAS(&As[bf][w*1024 + 512]), 16, 0, 0);
        __builtin_amdgcn_global_load_lds(GAS(B0b + (long)(n0 + rA     )*ldb + kt + cswz), LAS(&Bs[bf][w*1024      ]), 16, 0, 0);
        __builtin_amdgcn_global_load_lds(GAS(B0b + (long)(n0 + rA + 16)*ldb + kt + cswz), LAS(&Bs[bf][w*1024 + 512]), 16, 0, 0);
    };

    #pragma unroll
    for (int dpl = 0; dpl < NBUF - 1; ++dpl) stage(dpl, dpl);

    int buf = 0;
    for (int s = 0; s < NT; ++s) {
        if (NBUF >= 4 && s + 2 < NT) asm volatile("s_waitcnt vmcnt(8)" ::: "memory");
        else if (s + 1 < NT)         asm volatile("s_waitcnt vmcnt(4)" ::: "memory");
        else                         asm volatile("s_waitcnt vmcnt(0)" ::: "memory");
        __builtin_amdgcn_s_barrier();
        __builtin_amdgcn_sched_barrier(0);

        s8 aF[4], bF[4];
        #pragma unroll
        for (int m = 0; m < 4; ++m) aF[m] = *(const s8*)&As[buf][(wr*64 + m*16 + lr)*32 + swzr];
        #pragma unroll
        for (int n = 0; n < 4; ++n) bF[n] = *(const s8*)&Bs[buf][(wc*64 + n*16 + lr)*32 + swzr];

        if (s + NBUF - 1 < NT) {
            int bn = buf + NBUF - 1; if (bn >= NBUF) bn -= NBUF;
            stage(s + NBUF - 1, bn);
        }

        __builtin_amdgcn_s_setprio(1);
        #pragma unroll
        for (int m = 0; m < 4; ++m)
            #pragma unroll
            for (int n = 0; n < 4; ++n)
                acc[m][n] = __builtin_amdgcn_mfma_f32_16x16x32_bf16(aF[m], bF[n], acc[m][n], 0, 0, 0);
        __builtin_amdgcn_s_setprio(0);

        if (++buf == NBUF) buf = 0;
    }

    const int rbase = (l >> 4) * 4;
    #pragma unroll
    for (int m = 0; m < 4; ++m) {
        #pragma unroll
        for (int n = 0; n < 4; ++n) {
            const int row = m0 + wr*64 + m*16 + rbase;
            const int col = n0 + wc*64 + n*16 + lr;
            #pragma unroll
            for (int j = 0; j < 4; ++j) {
                float v = acc[m][n][j];
                if (BIAS == 1) v += bias[row + j];
                else if (BIAS == 2) v += bias[col];
                const long idx = (long)b*sC + (long)(row + j)*ldc + col;
                if (OUTF32) ((float*)Cv0)[idx] = v;
                else ((unsigned short*)Cv0)[idx] = f2bf(v);
            }
        }
    }
}

// ---------------- row softmax: zs[r][k] = scale * softmax_k(S[r][k]) ----------
__global__ __launch_bounds__(256) void row_softmax(
    const float* __restrict__ S, unsigned short* __restrict__ Z,
    const float* __restrict__ scale_p)
{
    const int wid = threadIdx.x >> 6, l = threadIdx.x & 63;
    const long row = (long)blockIdx.x * 4 + wid;   // 8192 rows total
    const float* src = S + row * 1024;
    f4 v[4];
    #pragma unroll
    for (int i = 0; i < 4; ++i) v[i] = *(const f4*)&src[(i*64 + l)*4];
    float m = -3.4e38f;
    #pragma unroll
    for (int i = 0; i < 4; ++i)
        #pragma unroll
        for (int j = 0; j < 4; ++j) m = fmaxf(m, v[i][j]);
    #pragma unroll
    for (int off = 32; off; off >>= 1) m = fmaxf(m, __shfl_xor(m, off));
    float s = 0.f;
    #pragma unroll
    for (int i = 0; i < 4; ++i)
        #pragma unroll
        for (int j = 0; j < 4; ++j) { v[i][j] = __expf(v[i][j] - m); s += v[i][j]; }
    #pragma unroll
    for (int off = 32; off; off >>= 1) s += __shfl_xor(s, off);
    const float c = scale_p[0] / s;
    #pragma unroll
    for (int i = 0; i < 4; ++i) {
        us4 o;
        #pragma unroll
        for (int j = 0; j < 4; ++j) o[j] = f2bf(v[i][j] * c);
        *(us4*)&Z[row*1024 + (long)(i*64 + l)*4] = o;
    }
}

// ---------------- column stats: online max+sum per column ---------------------
__global__ __launch_bounds__(256) void col_stats(
    const float* __restrict__ S, float* __restrict__ cm, float* __restrict__ cs)
{
    __shared__ float pm[4][64], ps[4][64];
    const int b  = blockIdx.y;
    const int ci = threadIdx.x & 63, ks = threadIdx.x >> 6;
    const int q  = blockIdx.x * 64 + ci;
    const float* Sb = S + (long)b * 1048576 + q;
    float m = -3.4e38f, s = 0.f;
    for (int k = ks*256; k < ks*256 + 256; ++k) {
        float v = Sb[(long)k * 1024];
        float dlt = v - m;
        float ed = __expf(-fabsf(dlt));
        if (dlt > 0.f) { s = s * ed + 1.f; m = v; } else s += ed;
    }
    pm[ks][ci] = m; ps[ks][ci] = s;
    __syncthreads();
    if (threadIdx.x < 64) {
        float M = pm[0][ci];
        #pragma unroll
        for (int i = 1; i < 4; ++i) M = fmaxf(M, pm[i][ci]);
        float Ssum = 0.f;
        #pragma unroll
        for (int i = 0; i < 4; ++i) Ssum += ps[i][ci] * __expf(pm[i][ci] - M);
        cm[b*1024 + q] = M;
        cs[b*1024 + q] = Ssum;
    }
}

// ------- column softmax write via LDS transpose (coalesced zc writes) ---------
__global__ __launch_bounds__(256) void col_write(
    const float* __restrict__ S, const float* __restrict__ cm,
    const float* __restrict__ cs, unsigned short* __restrict__ Z,
    const float* __restrict__ scale_p)
{
    __shared__ float tile[64][65];
    const int b  = blockIdx.z;
    const int q0 = blockIdx.x * 64;
    const int k0 = blockIdx.y * 64;
    const int t  = threadIdx.x;
    const float* Sb = S + (long)b * 1048576;
    // load 64(k) x 64(q) tile, coalesced f4 reads
    const int tq = t & 15, tr = t >> 4;   // tq: q-quad 0..15, tr: k-row 0..15
    #pragma unroll
    for (int ii = 0; ii < 4; ++ii) {
        const int kr = tr + ii*16;
        f4 v = *(const f4*)&Sb[(long)(k0 + kr)*1024 + q0 + tq*4];
        tile[kr][tq*4+0] = v[0]; tile[kr][tq*4+1] = v[1];
        tile[kr][tq*4+2] = v[2]; tile[kr][tq*4+3] = v[3];
    }
    __syncthreads();
    const int qr = t >> 2, kp = t & 3;    // qr 0..63, kp 0..3 (16-k slab each)
    const int q = q0 + qr;
    const float m   = cm[b*1024 + q];
    const float inv = scale_p[0] / cs[b*1024 + q];
    unsigned short* Zb = Z + (long)b*1048576 + (long)q*1024 + k0 + kp*16;
    us8 o0, o1;
    #pragma unroll
    for (int e = 0; e < 8; ++e) o0[e] = f2bf(inv * __expf(tile[kp*16 + e][qr] - m));
    #pragma unroll
    for (int e = 0; e < 8; ++e) o1[e] = f2bf(inv * __expf(tile[kp*16 + 8 + e][qr] - m));
    *(us8*)&Zb[0] = o0;
    *(us8*)&Zb[8] = o1;
}

// -----------------------------------------------------------------------------
extern "C" void kernel_launch(void* const* d_in, const int* in_sizes, int n_in,
                              void* d_out, int out_size, void* d_ws, size_t ws_size,
                              hipStream_t stream)
{
    const float* x     = (const float*)d_in[0];
    const float* w1    = (const float*)d_in[1];
    const float* b1    = (const float*)d_in[2];
    const float* wq    = (const float*)d_in[3];
    const float* bq    = (const float*)d_in[4];
    const float* wv    = (const float*)d_in[5];
    const float* bv    = (const float*)d_in[6];
    const float* w2    = (const float*)d_in[7];
    const float* b2    = (const float*)d_in[8];
    const float* alpha = (const float*)d_in[9];
    const float* beta  = (const float*)d_in[10];
    float* out = (float*)d_out;

    char* ws = (char*)d_ws;
    size_t off = 0;
    auto alloc = [&](size_t bytes) -> void* {
        void* p = ws + off; off += (bytes + 255) & ~(size_t)255; return p;
    };
    unsigned short* w1b   = (unsigned short*)alloc(1024L*256*2);      // .5 MB
    unsigned short* wqvb  = (unsigned short*)alloc(2048L*1024*2);     //  4 MB (wq||wv)
    unsigned short* w2b   = (unsigned short*)alloc(256L*1024*2);      // .5 MB
    float*          biasqv= (float*)alloc(2048L*4);                   //  8 KB
    float*          cmv   = (float*)alloc(8L*1024*4);                 // 32 KB
    float*          csv   = (float*)alloc(8L*1024*4);                 // 32 KB
    unsigned short* xTb   = (unsigned short*)alloc(8L*1024*256*2);    //  4 MB
    unsigned short* x1b   = (unsigned short*)alloc(8L*1024*1024*2);   // 16 MB
    unsigned short* x1tb  = (unsigned short*)alloc(8L*1024*1024*2);   // 16 MB
    unsigned short* gtb   = (unsigned short*)alloc(8L*1024*1024*2);   // 16 MB
    unsigned short* rtb   = (unsigned short*)alloc(8L*1024*1024*2);   // 16 MB
    float*          Sf    = (float*)alloc(8L*1024*1024*4);            // 32 MB
    // lifetime aliases:
    unsigned short* zsb = x1tb;                 // x1tb dead after gT/rT GEMM
    unsigned short* zcb = gtb;                  // gtb dead after S GEMM
    unsigned short* Ptb = (unsigned short*)Sf;  // Sf dead after softmaxes

    const long S1M = 1048576;

    conv_weights<<<2562, 256, 0, stream>>>(w1, wq, wv, w2, w1b, wqvb, wqvb + S1M, w2b, bq, bv, biasqv);
    transpose_x<<<dim3(32, 8, 8), 256, 0, stream>>>(x, xTb);

    // x1 = w1·xT^T + b1(row)               [chan,hw], z-batched (256 blocks)
    gemm256<1,0,0,1><<<dim3(8, 4, 8), 512, 0, stream>>>(
        w1b, xTb, nullptr, nullptr, 0, 262144, 256, 256, x1b, nullptr, S1M, 1024, b1, 4);
    // x1T = xT·w1^T + b1(col)              stacked M=8192 (256 blocks)
    gemm256<2,0,0,1><<<dim3(8, 32, 1), 512, 0, stream>>>(
        xTb, w1b, nullptr, nullptr, 0, 0, 256, 256, x1tb, nullptr, 0, 1024, b1, 4);
    // gT|rT = x1T·(wq||wv)^T + bias(col)   stacked M=8192, N=2048, split (512 blocks)
    gemm256<2,0,1,1><<<dim3(16, 32, 1), 512, 0, stream>>>(
        x1tb, wqvb, nullptr, nullptr, 0, 0, 1024, 1024, gtb, rtb, 0, 1024, biasqv, 16);
    // S = x1·gT^T (fp32)                   z-batched (256 blocks)
    gemm256<0,1,0,1><<<dim3(8, 4, 8), 512, 0, stream>>>(
        x1b, gtb, nullptr, nullptr, S1M, S1M, 1024, 1024, Sf, nullptr, S1M, 1024, nullptr, 16);
    // zs = alpha * row-softmax(S); zc = beta * col-softmax(S)   (C2 = S^T)
    row_softmax<<<2048, 256, 0, stream>>>(Sf, zsb, alpha);
    col_stats<<<dim3(16, 8), 256, 0, stream>>>(Sf, cmv, csv);
    col_write<<<dim3(16, 16, 8), 256, 0, stream>>>(Sf, cmv, csv, zcb, beta);
    // PT = rT·zs^T + zc·x1^T               dual-pass accumulate (256 blocks)
    gemm256<0,0,0,2><<<dim3(8, 4, 8), 512, 0, stream>>>(
        rtb, zsb, zcb, x1b, S1M, S1M, 1024, 1024, Ptb, nullptr, S1M, 1024, nullptr, 16);
    // out = w2·PT^T + b2(row), fp32        (128 blocks, depth-3)
    gemm_pipe<1,1,32,4><<<dim3(8, 2, 8), 256, 0, stream>>>(
        w2b, Ptb, 0, S1M, 1024, 1024, out, 262144, 1024, b2);
}

// Round 11
// 175.812 us; speedup vs baseline: 2.2110x; 1.0262x over previous
//
#include <hip/hip_runtime.h>
#include <hip/hip_bf16.h>

// B=8, C=256, H=W=32, N=HW=1024.
// Pipeline (all GEMMs C[M,N] = A[M,K] · Bt[N,K]^T, both K-contiguous):
//  xT    = transpose(x) bf16                      [8][1024,256]
//  x1    = w1·xT^T + b1(row)                      [8][chan,hw]
//  x1T   = xT·w1^T + b1(col)   (stacked M=8192)   [8][hw,chan]
//  gT|rT = x1T·(wq||wv)^T + (bq||bv)(col)  stacked M=8192, N=2048, split out
//          ^-- NEW: gemm8p 256x256 8-phase m201-style schedule (256 blocks)
//  S     = x1·gT^T (fp32)                         [8][chan,hw] ; C2 = S^T (algebra)
//  zs    = alpha * row-softmax(S)      bf16  -> x1tb (dead)
//  zc    = beta  * col-softmax(S)      bf16  -> gtb  (dead)
//  PT    = rT·zs^T + zc·x1^T           bf16  -> Sf   (dead)
//  out   = w2·PT^T + b2(row)           fp32
// gemm8p: BM=BN=256 BK=64, 8 waves (2Mx4N, 128x64/wave). LDS = 2 tile-dbuf x
// 2 K-half slots per matrix (128 KB). Phase=(tile,khalf,mhalf): {8|4 ds_read
// -> stage 1 half-slot (2 gload_lds) -> barrier -> lgkm(0) -> 16 MFMA ->
// barrier}; vmcnt(4) only at phases 4/8 (liveness+retirement hand-verified;
// >=4 loads always in flight). Tail stages wrap mod NT to keep counts uniform.

typedef __attribute__((ext_vector_type(4))) float f4;
typedef __attribute__((ext_vector_type(8))) short s8;
typedef __attribute__((ext_vector_type(4))) unsigned short us4;
typedef __attribute__((ext_vector_type(8))) unsigned short us8;

__device__ __forceinline__ unsigned short f2bf(float f) {
    __hip_bfloat16 h = __float2bfloat16(f);
    return __builtin_bit_cast(unsigned short, h);
}

#define GAS(p) ((const __attribute__((address_space(1))) unsigned int*)(p))
#define LAS(p) ((__attribute__((address_space(3))) unsigned int*)(p))

// ---------------- weight fp32 -> bf16 conversion + bias concat ----------------
__global__ __launch_bounds__(256) void conv_weights(
    const float* __restrict__ w1, const float* __restrict__ wq,
    const float* __restrict__ wv, const float* __restrict__ w2,
    unsigned short* __restrict__ w1b, unsigned short* __restrict__ wqb,
    unsigned short* __restrict__ wvb, unsigned short* __restrict__ w2b,
    const float* __restrict__ bq, const float* __restrict__ bv,
    float* __restrict__ biasqv)
{
    long i = (long)blockIdx.x * 256 + threadIdx.x;  // float4 index
    if (i >= 655360) {                               // bias concat: 512 f4
        long j = i - 655360;
        if (j < 512) {
            f4 v = (j < 256) ? ((const f4*)bq)[j] : ((const f4*)bv)[j - 256];
            ((f4*)biasqv)[j] = v;
        }
        return;
    }
    const float* src; unsigned short* dst; long base;
    if (i < 65536)               { src = w1; dst = w1b; base = 0; }
    else if (i < 65536+262144)   { src = wq; dst = wqb; base = 65536; }
    else if (i < 65536+524288)   { src = wv; dst = wvb; base = 65536+262144; }
    else                         { src = w2; dst = w2b; base = 65536+524288; }
    long j = i - base;
    f4 v = ((const f4*)src)[j];
    us4 o;
    #pragma unroll
    for (int k = 0; k < 4; ++k) o[k] = f2bf(v[k]);
    ((us4*)dst)[j] = o;
}

// ---------------- x [8][256][1024] fp32 -> xT [8][1024][256] bf16 -------------
__global__ __launch_bounds__(256) void transpose_x(
    const float* __restrict__ x, unsigned short* __restrict__ xT)
{
    __shared__ float tl[32][33];
    const int b  = blockIdx.z;
    const int q0 = blockIdx.x * 32;
    const int c0 = blockIdx.y * 32;
    const int tx = threadIdx.x & 31, ty = threadIdx.x >> 5;  // ty 0..7
    #pragma unroll
    for (int j = 0; j < 4; ++j)
        tl[ty + j*8][tx] = x[((long)(b*256 + c0 + ty + j*8))*1024 + q0 + tx];
    __syncthreads();
    #pragma unroll
    for (int j = 0; j < 4; ++j)
        xT[((long)(b*1024 + q0 + ty + j*8))*256 + c0 + tx] = f2bf(tl[tx][ty + j*8]);
}

// ============ 256x256 8-phase GEMM (m201-style), K=1024, stacked M ============
// BIAS: 0 none, 2 col. SPLIT: cols>=1024 -> Cv1. Output bf16.
template<int BIAS, int SPLIT>
__global__ __launch_bounds__(512, 2) void gemm8p(
    const unsigned short* __restrict__ A0, const unsigned short* __restrict__ Bt0,
    int lda, int ldb,
    void* __restrict__ Cv0, void* __restrict__ Cv1, int ldc,
    const float* __restrict__ bias)
{
    constexpr int NT = 16;                                   // K/64
    __shared__ __align__(16) unsigned short As[2][2][8192];  // [dbuf][kh][256*32] 64 KB
    __shared__ __align__(16) unsigned short Bs[2][2][8192];  // 64 KB

    // bijective XCD swizzle (nwg % 8 == 0)
    const int gx = gridDim.x, gy = gridDim.y;
    const int nwg = gx * gy;
    int d = blockIdx.x + gx * blockIdx.y;
    int swz = (d & 7) * (nwg >> 3) + (d >> 3);
    const int bx = swz % gx;
    const int by = swz / gx;

    const int m0 = by * 256;
    const int n0 = bx * 256;
    const int t  = threadIdx.x;
    const int w  = t >> 6, l = t & 63;
    const int wr = w >> 2, wc = w & 3;          // 2 M-waves x 4 N-waves
    const int lr = l & 15, lg = l >> 4;

    const unsigned short* Asrc = A0  + (long)m0 * lda;
    const unsigned short* Bsrc = Bt0 + (long)n0 * ldb;

    // staging: per wave 1 gload = 64 lanes x 16B = 16 rows of 64B (32 elems).
    // LDS linear dest (row = rb + l>>2, chunk cs = l&3); source chunk
    // pre-swizzled cs ^ ((row>>1)&3) = (l&3) ^ ((l>>3)&3).
    const int rl4 = l >> 2;
    const int gsw = ((l & 3) ^ ((l >> 3) & 3)) * 8;  // element offset
    const int rsw = (lr >> 1) & 3;                    // read-side XOR

    auto stage = [&](const unsigned short* src, int ld_, unsigned short* slot,
                     int sp, int kh) {                // one half-slot: 2 gloads
        #pragma unroll
        for (int i = 0; i < 2; ++i) {
            const int rb = i*128 + w*16;
            __builtin_amdgcn_global_load_lds(
                GAS(src + (long)(rb + rl4)*ld_ + sp*64 + kh*32 + gsw),
                LAS(slot + rb*32), 16, 0, 0);
        }
    };

    f4 acc[8][4];
    #pragma unroll
    for (int i = 0; i < 8; ++i)
        #pragma unroll
        for (int j = 0; j < 4; ++j) acc[i][j] = (f4){0.f, 0.f, 0.f, 0.f};

    s8 aF[4], bF[4];
    auto rdA = [&](int db, int kh, int mh) {
        #pragma unroll
        for (int m = 0; m < 4; ++m) {
            const int R = wr*128 + mh*64 + m*16 + lr;
            aF[m] = *(const s8*)&As[db][kh][R*32 + ((lg ^ rsw) * 8)];
        }
    };
    auto rdB = [&](int db, int kh) {
        #pragma unroll
        for (int n = 0; n < 4; ++n) {
            const int R = wc*64 + n*16 + lr;
            bF[n] = *(const s8*)&Bs[db][kh][R*32 + ((lg ^ rsw) * 8)];
        }
    };

#define MM8(MH)                                                                  \
    __builtin_amdgcn_s_setprio(1);                                               \
    _Pragma("unroll")                                                            \
    for (int m_ = 0; m_ < 4; ++m_)                                               \
        _Pragma("unroll")                                                        \
        for (int n_ = 0; n_ < 4; ++n_)                                           \
            acc[(MH)*4 + m_][n_] = __builtin_amdgcn_mfma_f32_16x16x32_bf16(      \
                aF[m_], bF[n_], acc[(MH)*4 + m_][n_], 0, 0, 0);                  \
    __builtin_amdgcn_s_setprio(0);

#define PH8(DB, KH, MH, RB, STG, VM)                                             \
    rdA(DB, KH, MH);                                                             \
    if (RB) rdB(DB, KH);                                                         \
    STG;                                                                         \
    __builtin_amdgcn_sched_barrier(0);                                           \
    __builtin_amdgcn_s_barrier();                                                \
    asm volatile("s_waitcnt lgkmcnt(0)" ::: "memory");                           \
    __builtin_amdgcn_sched_barrier(0);                                           \
    MM8(MH);                                                                     \
    VM;                                                                          \
    __builtin_amdgcn_s_barrier();

    // prologue: tile0 (both kh) + tile1 kh0 = 6 half-slots = 12 loads/wave.
    // vmcnt(4): loads 1-8 (tile0 complete) retired; remaining 4 = tile1 kh0
    // (exactly the steady-state role of "prev ph7,ph8").
    stage(Asrc, lda, &As[0][0][0], 0, 0);
    stage(Bsrc, ldb, &Bs[0][0][0], 0, 0);
    stage(Asrc, lda, &As[0][1][0], 0, 1);
    stage(Bsrc, ldb, &Bs[0][1][0], 0, 1);
    stage(Asrc, lda, &As[1][0][0], 1, 0);
    stage(Bsrc, ldb, &Bs[1][0][0], 1, 0);
    asm volatile("s_waitcnt vmcnt(4)" ::: "memory");
    __builtin_amdgcn_sched_barrier(0);
    __builtin_amdgcn_s_barrier();

    for (int j = 0; j < NT/2; ++j) {
        const int tb = 2*j + 1;
        const int t2 = (2*j + 2) & (NT - 1);   // wrap in tail (redundant loads,
        const int t3 = (2*j + 3) & (NT - 1);   // keeps vmcnt counts uniform)
        // ph1: tile even, kh0, mh0;  stage A[1][1] <- tb kh1 (read ph7)
        PH8(0,0,0, 1, stage(Asrc, lda, &As[1][1][0], tb, 1), (void)0)
        // ph2: kh0, mh1 (B reused); stage B[1][1] <- tb kh1 (read ph7/8)
        PH8(0,0,1, 0, stage(Bsrc, ldb, &Bs[1][1][0], tb, 1), (void)0)
        // ph3: kh1, mh0;            stage A[0][0] <- t2 kh0 (slot freed ph2)
        PH8(0,1,0, 1, stage(Asrc, lda, &As[0][0][0], t2, 0), (void)0)
        // ph4: kh1, mh1;            stage B[0][0] <- t2 kh0; vmcnt(4)
        PH8(0,1,1, 0, stage(Bsrc, ldb, &Bs[0][0][0], t2, 0),
            asm volatile("s_waitcnt vmcnt(4)" ::: "memory"))
        // ph5: tile odd, kh0, mh0;  stage A[0][1] <- t2 kh1 (slot freed ph4)
        PH8(1,0,0, 1, stage(Asrc, lda, &As[0][1][0], t2, 1), (void)0)
        // ph6: kh0, mh1;            stage B[0][1] <- t2 kh1
        PH8(1,0,1, 0, stage(Bsrc, ldb, &Bs[0][1][0], t2, 1), (void)0)
        // ph7: kh1, mh0;            stage A[1][0] <- t3 kh0 (slot freed ph6)
        PH8(1,1,0, 1, stage(Asrc, lda, &As[1][0][0], t3, 0), (void)0)
        // ph8: kh1, mh1;            stage B[1][0] <- t3 kh0; vmcnt(4)
        PH8(1,1,1, 0, stage(Bsrc, ldb, &Bs[1][0][0], t3, 0),
            asm volatile("s_waitcnt vmcnt(4)" ::: "memory"))
    }
#undef PH8
#undef MM8

    void* Cd = Cv0; int nbase = n0;
    if (SPLIT && n0 >= 1024) { Cd = Cv1; nbase = n0 - 1024; }

    const int rbase = lg * 4;
    #pragma unroll
    for (int mi = 0; mi < 8; ++mi) {
        #pragma unroll
        for (int n = 0; n < 4; ++n) {
            const int row  = m0 + wr*128 + mi*16 + rbase;
            const int col  = nbase + wc*64 + n*16 + lr;
            const int bcol = n0    + wc*64 + n*16 + lr;
            #pragma unroll
            for (int j = 0; j < 4; ++j) {
                float v = acc[mi][n][j];
                if (BIAS == 2) v += bias[bcol];
                ((unsigned short*)Cd)[(long)(row + j)*ldc + col] = f2bf(v);
            }
        }
    }
}

// ---------------- big-tile GEMM: 256x128, BK=64, 8 waves, piped reads ---------
// BIAS: 0 none, 1 row, 2 col. OUTF32: fp32 out. SPLIT: cols>=1024 -> Cv1.
// NPASS: 1 or 2 (dual accumulate). nt1: K-tiles (of 64) per pass (>= 3).
// Grid total MUST be % 8 == 0.
template<int BIAS, int OUTF32, int SPLIT, int NPASS>
__global__ __launch_bounds__(512, 2) void gemm256(
    const unsigned short* __restrict__ A0, const unsigned short* __restrict__ Bt0,
    const unsigned short* __restrict__ A1, const unsigned short* __restrict__ Bt1,
    long sA, long sB, int lda, int ldb,
    void* __restrict__ Cv0, void* __restrict__ Cv1, long sC, int ldc,
    const float* __restrict__ bias, int nt1)
{
    __shared__ __align__(16) unsigned short As[3][16384];   // 3 x 256x64 = 96 KB
    __shared__ __align__(16) unsigned short Bs[3][8192];    // 3 x 128x64 = 48 KB

    const int gx = gridDim.x, gy = gridDim.y;
    const int nwg = gx * gy * gridDim.z;
    int d = blockIdx.x + gx * (blockIdx.y + gy * blockIdx.z);
    int swz = (d & 7) * (nwg >> 3) + (d >> 3);
    const int bx = swz % gx; int tq = swz / gx;
    const int by = tq % gy;  const int bz = tq / gy;

    const int b  = bz;
    const int m0 = by * 256;
    const int n0 = bx * 128;
    const int t  = threadIdx.x;
    const int w  = t >> 6, l = t & 63;
    const int wr = w >> 1, wc = w & 1;          // 4 M-waves x 2 N-waves
    const int lr = l & 15, lg = l >> 4;

    const unsigned short* A0b = A0  + (long)b * sA;
    const unsigned short* B0b = Bt0 + (long)b * sB;
    const unsigned short* A1b = (NPASS > 1) ? A1  + (long)b * sA : nullptr;
    const unsigned short* B1b = (NPASS > 1) ? Bt1 + (long)b * sB : nullptr;

    const int rl  = l >> 3;
    const int gsw = ((l & 7) ^ (rl & 7)) * 8;

    const int NT = NPASS * nt1;

    auto stageA = [&](int sp, int bf) {
        const unsigned short* Ap = A0b; int kt = sp * 64;
        if (NPASS > 1 && sp >= nt1) { Ap = A1b; kt = (sp - nt1) * 64; }
        #pragma unroll
        for (int i = 0; i < 4; ++i) {
            const int rb = w*32 + i*8;
            __builtin_amdgcn_global_load_lds(GAS(Ap + (long)(m0 + rb + rl)*lda + kt + gsw),
                                             LAS(&As[bf][rb*64]), 16, 0, 0);
        }
    };
    auto stageB = [&](int sp, int bf) {
        const unsigned short* Bp = B0b; int kt = sp * 64;
        if (NPASS > 1 && sp >= nt1) { Bp = B1b; kt = (sp - nt1) * 64; }
        #pragma unroll
        for (int i = 0; i < 2; ++i) {
            const int rb = w*16 + i*8;
            __builtin_amdgcn_global_load_lds(GAS(Bp + (long)(n0 + rb + rl)*ldb + kt + gsw),
                                             LAS(&Bs[bf][rb*64]), 16, 0, 0);
        }
    };

    f4 acc[4][4];
    #pragma unroll
    for (int i = 0; i < 4; ++i)
        #pragma unroll
        for (int j = 0; j < 4; ++j) acc[i][j] = (f4){0.f, 0.f, 0.f, 0.f};

    stageA(0, 0); stageB(0, 0);
    stageA(1, 1); stageB(1, 1);
    asm volatile("s_waitcnt vmcnt(6)" ::: "memory");
    __builtin_amdgcn_sched_barrier(0);
    __builtin_amdgcn_s_barrier();

    s8 a0[4], b0[4], a1f[4], b1f[4];

    #pragma unroll
    for (int m = 0; m < 4; ++m) {
        const int R = wr*64 + m*16 + lr;
        a0[m] = *(const s8*)&As[0][R*64 + ((lg ^ (R & 7)) * 8)];
    }
    #pragma unroll
    for (int n = 0; n < 4; ++n) {
        const int R = wc*64 + n*16 + lr;
        b0[n] = *(const s8*)&Bs[0][R*64 + ((lg ^ (R & 7)) * 8)];
    }
    asm volatile("s_waitcnt lgkmcnt(0)" ::: "memory");
    __builtin_amdgcn_sched_barrier(0);

    int buf = 0;
    for (int s = 0; s < NT; ++s) {
        int bn = buf + 2; if (bn >= 3) bn -= 3;
        int bx1 = buf + 1; if (bx1 >= 3) bx1 -= 3;

        #pragma unroll
        for (int m = 0; m < 4; ++m) {
            const int R = wr*64 + m*16 + lr;
            a1f[m] = *(const s8*)&As[buf][R*64 + (((4 + lg) ^ (R & 7)) * 8)];
        }
        #pragma unroll
        for (int n = 0; n < 4; ++n) {
            const int R = wc*64 + n*16 + lr;
            b1f[n] = *(const s8*)&Bs[buf][R*64 + (((4 + lg) ^ (R & 7)) * 8)];
        }
        if (s + 2 < NT) stageA(s + 2, bn);
        __builtin_amdgcn_s_setprio(1);
        #pragma unroll
        for (int m = 0; m < 4; ++m)
            #pragma unroll
            for (int n = 0; n < 4; ++n)
                acc[m][n] = __builtin_amdgcn_mfma_f32_16x16x32_bf16(a0[m], b0[n], acc[m][n], 0, 0, 0);
        __builtin_amdgcn_s_setprio(0);
        asm volatile("s_waitcnt lgkmcnt(0)" ::: "memory");
        __builtin_amdgcn_sched_barrier(0);

        if (s + 1 < NT) {
            if (s + 2 < NT) asm volatile("s_waitcnt vmcnt(4)" ::: "memory");
            else            asm volatile("s_waitcnt vmcnt(0)" ::: "memory");
            __builtin_amdgcn_sched_barrier(0);
            __builtin_amdgcn_s_barrier();
            #pragma unroll
            for (int m = 0; m < 4; ++m) {
                const int R = wr*64 + m*16 + lr;
                a0[m] = *(const s8*)&As[bx1][R*64 + ((lg ^ (R & 7)) * 8)];
            }
            #pragma unroll
            for (int n = 0; n < 4; ++n) {
                const int R = wc*64 + n*16 + lr;
                b0[n] = *(const s8*)&Bs[bx1][R*64 + ((lg ^ (R & 7)) * 8)];
            }
            if (s + 2 < NT) stageB(s + 2, bn);
            __builtin_amdgcn_s_setprio(1);
            #pragma unroll
            for (int m = 0; m < 4; ++m)
                #pragma unroll
                for (int n = 0; n < 4; ++n)
                    acc[m][n] = __builtin_amdgcn_mfma_f32_16x16x32_bf16(a1f[m], b1f[n], acc[m][n], 0, 0, 0);
            __builtin_amdgcn_s_setprio(0);
            asm volatile("s_waitcnt lgkmcnt(0)" ::: "memory");
            __builtin_amdgcn_sched_barrier(0);
        } else {
            __builtin_amdgcn_s_setprio(1);
            #pragma unroll
            for (int m = 0; m < 4; ++m)
                #pragma unroll
                for (int n = 0; n < 4; ++n)
                    acc[m][n] = __builtin_amdgcn_mfma_f32_16x16x32_bf16(a1f[m], b1f[n], acc[m][n], 0, 0, 0);
            __builtin_amdgcn_s_setprio(0);
        }

        buf = bx1;
    }

    void* Cd = Cv0; int nbase = n0;
    if (SPLIT && n0 >= 1024) { Cd = Cv1; nbase = n0 - 1024; }

    const int rbase = lg * 4;
    #pragma unroll
    for (int m = 0; m < 4; ++m) {
        #pragma unroll
        for (int n = 0; n < 4; ++n) {
            const int row  = m0 + wr*64 + m*16 + rbase;
            const int col  = nbase + wc*64 + n*16 + lr;
            const int bcol = n0    + wc*64 + n*16 + lr;
            #pragma unroll
            for (int j = 0; j < 4; ++j) {
                float v = acc[m][n][j];
                if (BIAS == 1) v += bias[row + j];
                else if (BIAS == 2) v += bias[bcol];
                const long idx = (long)b*sC + (long)(row + j)*ldc + col;
                if (OUTF32) ((float*)Cd)[idx] = v;
                else ((unsigned short*)Cd)[idx] = f2bf(v);
            }
        }
    }
}

// ---------------- 128x128 pipelined GEMM (small shapes: out projection) -------
template<int BIAS, int OUTF32, int NT1, int NBUF>
__global__ __launch_bounds__(256) void gemm_pipe(
    const unsigned short* __restrict__ A0, const unsigned short* __restrict__ Bt0,
    long sA, long sB, int lda, int ldb,
    void* __restrict__ Cv0, long sC, int ldc,
    const float* __restrict__ bias)
{
    constexpr int NT = NT1;
    __shared__ __align__(16) unsigned short As[NBUF][4096];
    __shared__ __align__(16) unsigned short Bs[NBUF][4096];

    const int gx = gridDim.x, gy = gridDim.y;
    const int nwg = gx * gy * gridDim.z;
    int d = blockIdx.x + gx * (blockIdx.y + gy * blockIdx.z);
    int swz = (d & 7) * (nwg >> 3) + (d >> 3);
    const int bx = swz % gx; int tq = swz / gx;
    const int by = tq % gy;  const int bz = tq / gy;

    const int b  = bz;
    const int m0 = by * 128;
    const int n0 = bx * 128;
    const int t  = threadIdx.x;
    const int w  = t >> 6, l = t & 63;
    const int wr = w >> 1, wc = w & 1;
    const int lr = l & 15;

    const unsigned short* A0b = A0  + (long)b * sA;
    const unsigned short* B0b = Bt0 + (long)b * sB;

    const int rA   = w*32 + (l >> 2);
    const int cswz = ((l & 3) ^ ((l >> 3) & 3)) * 8;
    const int swzr = (((l >> 4) ^ ((lr >> 1) & 3)) * 8);

    f4 acc[4][4];
    #pragma unroll
    for (int i = 0; i < 4; ++i)
        #pragma unroll
        for (int j = 0; j < 4; ++j) acc[i][j] = (f4){0.f, 0.f, 0.f, 0.f};

    auto stage = [&](int sp, int bf) {
        const int kt = sp * 32;
        __builtin_amdgcn_global_load_lds(GAS(A0b + (long)(m0 + rA     )*lda + kt + cswz), LAS(&As[bf][w*1024      ]), 16, 0, 0);
        __builtin_amdgcn_global_load_lds(GAS(A0b + (long)(m0 + rA + 16)*lda + kt + cswz), LAS(&As[bf][w*1024 + 512]), 16, 0, 0);
        __builtin_amdgcn_global_load_lds(GAS(B0b + (long)(n0 + rA     )*ldb + kt + cswz), LAS(&Bs[bf][w*1024      ]), 16, 0, 0);
        __builtin_amdgcn_global_load_lds(GAS(B0b + (long)(n0 + rA + 16)*ldb + kt + cswz), LAS(&Bs[bf][w*1024 + 512]), 16, 0, 0);
    };

    #pragma unroll
    for (int dpl = 0; dpl < NBUF - 1; ++dpl) stage(dpl, dpl);

    int buf = 0;
    for (int s = 0; s < NT; ++s) {
        if (NBUF >= 4 && s + 2 < NT) asm volatile("s_waitcnt vmcnt(8)" ::: "memory");
        else if (s + 1 < NT)         asm volatile("s_waitcnt vmcnt(4)" ::: "memory");
        else                         asm volatile("s_waitcnt vmcnt(0)" ::: "memory");
        __builtin_amdgcn_s_barrier();
        __builtin_amdgcn_sched_barrier(0);

        s8 aF[4], bF[4];
        #pragma unroll
        for (int m = 0; m < 4; ++m) aF[m] = *(const s8*)&As[buf][(wr*64 + m*16 + lr)*32 + swzr];
        #pragma unroll
        for (int n = 0; n < 4; ++n) bF[n] = *(const s8*)&Bs[buf][(wc*64 + n*16 + lr)*32 + swzr];

        if (s + NBUF - 1 < NT) {
            int bn = buf + NBUF - 1; if (bn >= NBUF) bn -= NBUF;
            stage(s + NBUF - 1, bn);
        }

        __builtin_amdgcn_s_setprio(1);
        #pragma unroll
        for (int m = 0; m < 4; ++m)
            #pragma unroll
            for (int n = 0; n < 4; ++n)
                acc[m][n] = __builtin_amdgcn_mfma_f32_16x16x32_bf16(aF[m], bF[n], acc[m][n], 0, 0, 0);
        __builtin_amdgcn_s_setprio(0);

        if (++buf == NBUF) buf = 0;
    }

    const int rbase = (l >> 4) * 4;
    #pragma unroll
    for (int m = 0; m < 4; ++m) {
        #pragma unroll
        for (int n = 0; n < 4; ++n) {
            const int row = m0 + wr*64 + m*16 + rbase;
            const int col = n0 + wc*64 + n*16 + lr;
            #pragma unroll
            for (int j = 0; j < 4; ++j) {
                float v = acc[m][n][j];
                if (BIAS == 1) v += bias[row + j];
                else if (BIAS == 2) v += bias[col];
                const long idx = (long)b*sC + (long)(row + j)*ldc + col;
                if (OUTF32) ((float*)Cv0)[idx] = v;
                else ((unsigned short*)Cv0)[idx] = f2bf(v);
            }
        }
    }
}

// ---------------- row softmax: zs[r][k] = scale * softmax_k(S[r][k]) ----------
__global__ __launch_bounds__(256) void row_softmax(
    const float* __restrict__ S, unsigned short* __restrict__ Z,
    const float* __restrict__ scale_p)
{
    const int wid = threadIdx.x >> 6, l = threadIdx.x & 63;
    const long row = (long)blockIdx.x * 4 + wid;   // 8192 rows total
    const float* src = S + row * 1024;
    f4 v[4];
    #pragma unroll
    for (int i = 0; i < 4; ++i) v[i] = *(const f4*)&src[(i*64 + l)*4];
    float m = -3.4e38f;
    #pragma unroll
    for (int i = 0; i < 4; ++i)
        #pragma unroll
        for (int j = 0; j < 4; ++j) m = fmaxf(m, v[i][j]);
    #pragma unroll
    for (int off = 32; off; off >>= 1) m = fmaxf(m, __shfl_xor(m, off));
    float s = 0.f;
    #pragma unroll
    for (int i = 0; i < 4; ++i)
        #pragma unroll
        for (int j = 0; j < 4; ++j) { v[i][j] = __expf(v[i][j] - m); s += v[i][j]; }
    #pragma unroll
    for (int off = 32; off; off >>= 1) s += __shfl_xor(s, off);
    const float c = scale_p[0] / s;
    #pragma unroll
    for (int i = 0; i < 4; ++i) {
        us4 o;
        #pragma unroll
        for (int j = 0; j < 4; ++j) o[j] = f2bf(v[i][j] * c);
        *(us4*)&Z[row*1024 + (long)(i*64 + l)*4] = o;
    }
}

// ---------------- column stats: online max+sum per column ---------------------
__global__ __launch_bounds__(256) void col_stats(
    const float* __restrict__ S, float* __restrict__ cm, float* __restrict__ cs)
{
    __shared__ float pm[4][64], ps[4][64];
    const int b  = blockIdx.y;
    const int ci = threadIdx.x & 63, ks = threadIdx.x >> 6;
    const int q  = blockIdx.x * 64 + ci;
    const float* Sb = S + (long)b * 1048576 + q;
    float m = -3.4e38f, s = 0.f;
    for (int k = ks*256; k < ks*256 + 256; ++k) {
        float v = Sb[(long)k * 1024];
        float dlt = v - m;
        float ed = __expf(-fabsf(dlt));
        if (dlt > 0.f) { s = s * ed + 1.f; m = v; } else s += ed;
    }
    pm[ks][ci] = m; ps[ks][ci] = s;
    __syncthreads();
    if (threadIdx.x < 64) {
        float M = pm[0][ci];
        #pragma unroll
        for (int i = 1; i < 4; ++i) M = fmaxf(M, pm[i][ci]);
        float Ssum = 0.f;
        #pragma unroll
        for (int i = 0; i < 4; ++i) Ssum += ps[i][ci] * __expf(pm[i][ci] - M);
        cm[b*1024 + q] = M;
        cs[b*1024 + q] = Ssum;
    }
}

// ------- column softmax write via LDS transpose (coalesced zc writes) ---------
__global__ __launch_bounds__(256) void col_write(
    const float* __restrict__ S, const float* __restrict__ cm,
    const float* __restrict__ cs, unsigned short* __restrict__ Z,
    const float* __restrict__ scale_p)
{
    __shared__ float tile[64][65];
    const int b  = blockIdx.z;
    const int q0 = blockIdx.x * 64;
    const int k0 = blockIdx.y * 64;
    const int t  = threadIdx.x;
    const float* Sb = S + (long)b * 1048576;
    const int tq = t & 15, tr = t >> 4;
    #pragma unroll
    for (int ii = 0; ii < 4; ++ii) {
        const int kr = tr + ii*16;
        f4 v = *(const f4*)&Sb[(long)(k0 + kr)*1024 + q0 + tq*4];
        tile[kr][tq*4+0] = v[0]; tile[kr][tq*4+1] = v[1];
        tile[kr][tq*4+2] = v[2]; tile[kr][tq*4+3] = v[3];
    }
    __syncthreads();
    const int qr = t >> 2, kp = t & 3;
    const int q = q0 + qr;
    const float m   = cm[b*1024 + q];
    const float inv = scale_p[0] / cs[b*1024 + q];
    unsigned short* Zb = Z + (long)b*1048576 + (long)q*1024 + k0 + kp*16;
    us8 o0, o1;
    #pragma unroll
    for (int e = 0; e < 8; ++e) o0[e] = f2bf(inv * __expf(tile[kp*16 + e][qr] - m));
    #pragma unroll
    for (int e = 0; e < 8; ++e) o1[e] = f2bf(inv * __expf(tile[kp*16 + 8 + e][qr] - m));
    *(us8*)&Zb[0] = o0;
    *(us8*)&Zb[8] = o1;
}

// -----------------------------------------------------------------------------
extern "C" void kernel_launch(void* const* d_in, const int* in_sizes, int n_in,
                              void* d_out, int out_size, void* d_ws, size_t ws_size,
                              hipStream_t stream)
{
    const float* x     = (const float*)d_in[0];
    const float* w1    = (const float*)d_in[1];
    const float* b1    = (const float*)d_in[2];
    const float* wq    = (const float*)d_in[3];
    const float* bq    = (const float*)d_in[4];
    const float* wv    = (const float*)d_in[5];
    const float* bv    = (const float*)d_in[6];
    const float* w2    = (const float*)d_in[7];
    const float* b2    = (const float*)d_in[8];
    const float* alpha = (const float*)d_in[9];
    const float* beta  = (const float*)d_in[10];
    float* out = (float*)d_out;

    char* ws = (char*)d_ws;
    size_t off = 0;
    auto alloc = [&](size_t bytes) -> void* {
        void* p = ws + off; off += (bytes + 255) & ~(size_t)255; return p;
    };
    unsigned short* w1b   = (unsigned short*)alloc(1024L*256*2);      // .5 MB
    unsigned short* wqvb  = (unsigned short*)alloc(2048L*1024*2);     //  4 MB (wq||wv)
    unsigned short* w2b   = (unsigned short*)alloc(256L*1024*2);      // .5 MB
    float*          biasqv= (float*)alloc(2048L*4);                   //  8 KB
    float*          cmv   = (float*)alloc(8L*1024*4);                 // 32 KB
    float*          csv   = (float*)alloc(8L*1024*4);                 // 32 KB
    unsigned short* xTb   = (unsigned short*)alloc(8L*1024*256*2);    //  4 MB
    unsigned short* x1b   = (unsigned short*)alloc(8L*1024*1024*2);   // 16 MB
    unsigned short* x1tb  = (unsigned short*)alloc(8L*1024*1024*2);   // 16 MB
    unsigned short* gtb   = (unsigned short*)alloc(8L*1024*1024*2);   // 16 MB
    unsigned short* rtb   = (unsigned short*)alloc(8L*1024*1024*2);   // 16 MB
    float*          Sf    = (float*)alloc(8L*1024*1024*4);            // 32 MB
    // lifetime aliases:
    unsigned short* zsb = x1tb;                 // x1tb dead after gT/rT GEMM
    unsigned short* zcb = gtb;                  // gtb dead after S GEMM
    unsigned short* Ptb = (unsigned short*)Sf;  // Sf dead after softmaxes

    const long S1M = 1048576;

    conv_weights<<<2562, 256, 0, stream>>>(w1, wq, wv, w2, w1b, wqvb, wqvb + S1M, w2b, bq, bv, biasqv);
    transpose_x<<<dim3(32, 8, 8), 256, 0, stream>>>(x, xTb);

    // x1 = w1·xT^T + b1(row)               [chan,hw], z-batched (256 blocks)
    gemm256<1,0,0,1><<<dim3(8, 4, 8), 512, 0, stream>>>(
        w1b, xTb, nullptr, nullptr, 0, 262144, 256, 256, x1b, nullptr, S1M, 1024, b1, 4);
    // x1T = xT·w1^T + b1(col)              stacked M=8192 (256 blocks)
    gemm256<2,0,0,1><<<dim3(8, 32, 1), 512, 0, stream>>>(
        xTb, w1b, nullptr, nullptr, 0, 0, 256, 256, x1tb, nullptr, 0, 1024, b1, 4);
    // gT|rT = x1T·(wq||wv)^T + bias(col)   stacked M=8192, N=2048, split
    // NEW: 256x256 8-phase kernel, grid (8,32) = 256 blocks
    gemm8p<2,1><<<dim3(8, 32), 512, 0, stream>>>(
        x1tb, wqvb, 1024, 1024, gtb, rtb, 1024, biasqv);
    // S = x1·gT^T (fp32)                   z-batched (256 blocks)
    gemm256<0,1,0,1><<<dim3(8, 4, 8), 512, 0, stream>>>(
        x1b, gtb, nullptr, nullptr, S1M, S1M, 1024, 1024, Sf, nullptr, S1M, 1024, nullptr, 16);
    // zs = alpha * row-softmax(S); zc = beta * col-softmax(S)   (C2 = S^T)
    row_softmax<<<2048, 256, 0, stream>>>(Sf, zsb, alpha);
    col_stats<<<dim3(16, 8), 256, 0, stream>>>(Sf, cmv, csv);
    col_write<<<dim3(16, 16, 8), 256, 0, stream>>>(Sf, cmv, csv, zcb, beta);
    // PT = rT·zs^T + zc·x1^T               dual-pass accumulate (256 blocks)
    gemm256<0,0,0,2><<<dim3(8, 4, 8), 512, 0, stream>>>(
        rtb, zsb, zcb, x1b, S1M, S1M, 1024, 1024, Ptb, nullptr, S1M, 1024, nullptr, 16);
    // out = w2·PT^T + b2(row), fp32        (128 blocks, depth-3)
    gemm_pipe<1,1,32,4><<<dim3(8, 2, 8), 256, 0, stream>>>(
        w2b, Ptb, 0, S1M, 1024, 1024, out, 262144, 1024, b2);
}